// Round 3
// baseline (277.886 us; speedup 1.0000x reference)
//
#include <hip/hip_runtime.h>
#include <math.h>

#define B_ 64
#define N_ 512
#define P_ 256
#define E_ 4096
#define F_ 32
#define H_ 64
#define W_ 8
#define G_ 64
#define RH_ 256

// ---- workspace layout (float offsets) ----
#define X_OFF   0
#define T4_OFF  (X_OFF + N_*B_*F_)       // x:  [n][b][f]
#define T3_OFF  (T4_OFF + N_*B_*H_)      // t4: [n][b][h] (t2 folded in)
#define KB_OFF  (T3_OFF + P_*B_*H_)      // t3: [p][b][h]
#define KW_OFF  (KB_OFF + E_*H_)         // kb: [e][h]
#define YG_OFF  (KW_OFF + E_*B_*W_)      // (kw slot unused now, kept for layout stability)
#define HB_OFF  (YG_OFF + B_*P_*G_)      // yg: [b][p*64+g]
#define RES_OFF (HB_OFF + B_*RH_)        // hbuf: [b][rh]
#define INT_OFF (RES_OFF + 4*B_*G_)      // res4: [pq][b][g]
// int region at INT_OFF: lidx[4096] | ridx[4096] | part_start[512] | pe2[4096 int2]
// r0 partials (256*16384 floats = 16 MB) alias X_OFF.. (x/t4/t3/kb dead after k_eagg)

// ---------------------------------------------------------------------------
__global__ __launch_bounds__(256) void k_decode(const float* __restrict__ linc,
    const float* __restrict__ rinc, int* __restrict__ lidx, int* __restrict__ ridx) {
  int i4 = blockIdx.x * 256 + threadIdx.x;
  const int L4 = (P_ * E_) / 4;  // 262144
  if (i4 < L4) {
    float4 v = ((const float4*)linc)[i4];
    int i = i4 * 4;
    int p = i >> 12, e = i & 4095;
    if (v.x != 0.0f) lidx[e]     = p;
    if (v.y != 0.0f) lidx[e + 1] = p;
    if (v.z != 0.0f) lidx[e + 2] = p;
    if (v.w != 0.0f) lidx[e + 3] = p;
  } else {
    int j4 = i4 - L4;
    float4 v = ((const float4*)rinc)[j4];
    int j = j4 * 4;
    int e = j >> 9, n = j & 511;
    if (v.x != 0.0f) ridx[e] = n;
    if (v.y != 0.0f) ridx[e] = n + 1;
    if (v.z != 0.0f) ridx[e] = n + 2;
    if (v.w != 0.0f) ridx[e] = n + 3;
  }
}

// Counting-sort edges by partition. Single block of 1024.
// Emits packed (e, r) pairs so k_eagg has no dependent index chain.
__global__ __launch_bounds__(1024) void k_lists(const int* __restrict__ lidx,
    const int* __restrict__ ridx, int* __restrict__ part_start,
    int2* __restrict__ pe2) {
  __shared__ int cnt[256];
  __shared__ int buf[256];
  __shared__ int cur[256];
  int t = threadIdx.x;
  if (t < 256) cnt[t] = 0;
  __syncthreads();
  for (int e = t; e < E_; e += 1024) atomicAdd(&cnt[lidx[e]], 1);
  __syncthreads();
  if (t < 256) buf[t] = cnt[t];
  __syncthreads();
  for (int off = 1; off < 256; off <<= 1) {
    int add = 0;
    if (t < 256 && t >= off) add = buf[t - off];
    __syncthreads();
    if (t < 256) buf[t] += add;
    __syncthreads();
  }
  if (t < 256) {
    part_start[t + 1] = buf[t];
    if (t == 0) part_start[0] = 0;
    cur[t] = buf[t] - cnt[t];
  }
  __syncthreads();
  for (int e = t; e < E_; e += 1024) {
    int p = lidx[e];
    int pos = atomicAdd(&cur[p], 1);
    pe2[pos] = make_int2(e, ridx[e]);
  }
}

// Grouped conv (K=16, VALID, 1 out pos) + bias + relu -> x[n][b][f]
__global__ __launch_bounds__(256) void k_conv(const float* __restrict__ x1,
    const float* __restrict__ conv_w, const float* __restrict__ conv_b,
    float* __restrict__ x) {
  __shared__ float wsm[32 * 132];
  __shared__ float xsm[8192];
  int n = blockIdx.x, t = threadIdx.x;
  for (int i = t; i < 1024; i += 256) {
    int f = i >> 5, j = i & 31;
    ((float4*)wsm)[f * 33 + j] = ((const float4*)(conv_w + n * 4096))[i];
  }
  for (int i = t; i < 2048; i += 256) {
    int b = i >> 5, j = i & 31;
    ((float4*)xsm)[i] = ((const float4*)(x1 + b * 65536 + n * 128))[j];
  }
  __syncthreads();
  int f = t & 31, bq = t >> 5;
  float cb = conv_b[n * 32 + f];
  float acc[8];
#pragma unroll
  for (int bi = 0; bi < 8; bi++) acc[bi] = cb;
  const float4* wf4 = (const float4*)wsm + f * 33;
  const float4* xb4 = (const float4*)xsm + bq * 256;
#pragma unroll 4
  for (int k4 = 0; k4 < 32; k4++) {
    float4 wv = wf4[k4];
#pragma unroll
    for (int bi = 0; bi < 8; bi++) {
      float4 xv = xb4[bi * 32 + k4];
      acc[bi] += wv.x * xv.x + wv.y * xv.y + wv.z * xv.z + wv.w * xv.w;
    }
  }
#pragma unroll
  for (int bi = 0; bi < 8; bi++) {
    int b = bq * 8 + bi;
    x[n * 2048 + b * 32 + f] = fmaxf(acc[bi], 0.0f);
  }
}

// blocks [0,512): t4[n][b][h] = x[n]@k4_w^T + x2@k2_w^T
// blocks [512,768): t3[p][b][h] = x[pidx[p]]@k3_w^T
// blocks [768,1792): kb[e][h] = ef[e,:8]@k1_w^T + k1_b
// blocks [1792,1856): hbuf[b][rh] = x2@r1_w^T + r1_b + cap@r2_w^T
__global__ __launch_bounds__(256) void k_prep(
    const float* __restrict__ x, const int* __restrict__ pidx,
    const float* __restrict__ k3_w, const float* __restrict__ k4_w,
    const float* __restrict__ x2, const float* __restrict__ k2_w,
    const float* __restrict__ ef, const float* __restrict__ k1_w,
    const float* __restrict__ k1_b,
    const float* __restrict__ r1_w, const float* __restrict__ r1_b,
    const float* __restrict__ r2_w, const float* __restrict__ cap,
    float* __restrict__ t4, float* __restrict__ t3, float* __restrict__ kb,
    float* __restrict__ hbuf) {
  __shared__ float xsh[2048];
  __shared__ float wsh[64 * 36];
  __shared__ float x2s[512];
  __shared__ float k2s[512];
  int blk = blockIdx.x, t = threadIdx.x;
  if (blk < 768) {
    bool isT4 = blk < 512;
    int n = isT4 ? blk : pidx[blk - 512];
    const float* wmat = isT4 ? k4_w : k3_w;
    float* outp = isT4 ? (t4 + blk * 4096) : (t3 + (blk - 512) * 4096);
    for (int i = t; i < 512; i += 256) {
      ((float4*)xsh)[i] = ((const float4*)(x + n * 2048))[i];
      int h = i >> 3, j = i & 7;
      ((float4*)wsh)[h * 9 + j] = ((const float4*)wmat)[i];
    }
    if (isT4) {
      for (int i = t; i < 128; i += 256) {
        ((float4*)x2s)[i] = ((const float4*)x2)[i];
        ((float4*)k2s)[i] = ((const float4*)k2_w)[i];
      }
    }
    __syncthreads();
    int h = t & 63, bq = t >> 6;
    float wreg[32];
#pragma unroll
    for (int j = 0; j < 8; j++) {
      float4 v = ((float4*)wsh)[h * 9 + j];
      wreg[4 * j] = v.x; wreg[4 * j + 1] = v.y; wreg[4 * j + 2] = v.z; wreg[4 * j + 3] = v.w;
    }
    float w2[8];
    if (isT4) {
      float4 u = ((float4*)k2s)[h * 2], v = ((float4*)k2s)[h * 2 + 1];
      w2[0] = u.x; w2[1] = u.y; w2[2] = u.z; w2[3] = u.w;
      w2[4] = v.x; w2[5] = v.y; w2[6] = v.z; w2[7] = v.w;
    }
    for (int bi = 0; bi < 16; bi++) {
      int b = bq * 16 + bi;
      float acc = 0.0f;
#pragma unroll
      for (int j = 0; j < 8; j++) {
        float4 xv = ((float4*)xsh)[b * 8 + j];
        acc += xv.x * wreg[4 * j] + xv.y * wreg[4 * j + 1] +
               xv.z * wreg[4 * j + 2] + xv.w * wreg[4 * j + 3];
      }
      if (isT4) {
        float4 u = ((float4*)x2s)[b * 2], v = ((float4*)x2s)[b * 2 + 1];
        acc += u.x * w2[0] + u.y * w2[1] + u.z * w2[2] + u.w * w2[3] +
               v.x * w2[4] + v.y * w2[5] + v.z * w2[6] + v.w * w2[7];
      }
      outp[b * 64 + h] = acc;
    }
  } else if (blk < 1792) {
    int o = (blk - 768) * 256 + t;
    int e = o >> 6, h = o & 63;
    float acc = k1_b[h];
    const float* er = ef + e * 9;
    const float* kr = k1_w + h * 8;
#pragma unroll
    for (int d = 0; d < 8; d++) acc += er[d] * kr[d];
    kb[o] = acc;
  } else {
    int o = (blk - 1792) * 256 + t;
    int rh = o & 255;
    float acc = r1_b[rh];
    const float* xr = x2 + (o >> 8) * 8;
    const float* rr = r1_w + rh * 8;
#pragma unroll
    for (int d = 0; d < 8; d++) acc += xr[d] * rr[d];
    const float* r2r = r2_w + rh * 256;
    for (int p4 = 0; p4 < 64; p4++) {
      float4 cv = ((const float4*)cap)[p4];
      float4 rv = ((const float4*)r2r)[p4];
      acc += cv.x * rv.x + cv.y * rv.y + cv.z * rv.z + cv.w * rv.w;
    }
    hbuf[o] = acc;
  }
}

// Fused edge-MLP + aggregation + gc GEMM, one block (512 thr) per partition.
// Laneing: s = t&7 owns h in [s*8, s*8+8) and w = s; b = t>>3 is the batch row.
// k5_w slice (8w x 8h) + t3 fragment live in registers: ZERO LDS in main loop.
// __launch_bounds__(512,2): VGPR cap 256 so the ~175-reg loop does NOT spill.
// Edge descriptors are packed int2 (e,r) -> one independent prefetchable load.
// acc (32 f per thread, fp32) -> LDS fp32 [64b][256k] (s-fold swizzle) -> gc GEMM.
__global__ __launch_bounds__(512, 2) void k_eagg(
    const float* __restrict__ x, const float* __restrict__ kb,
    const float* __restrict__ t3, const float* __restrict__ t4,
    const float* __restrict__ k5_w, const float* __restrict__ k5_b,
    const int2* __restrict__ pe2, const int* __restrict__ part_start,
    const float* __restrict__ gc_w, const float* __restrict__ gc_b,
    float* __restrict__ yg) {
  __shared__ float accS[64 * 256];   // fp32 [b][kcol*4], col = s*8 | ((j^s^b)&7)
  int p = blockIdx.x, t = threadIdx.x;
  int s = t & 7, b = t >> 3;
  int h0 = s * 8;
  // hoist k5 slice [w][h0..h0+7] (64 regs) and t3 fragment (8 regs)
  float4 k5a[8], k5c[8];
#pragma unroll
  for (int w = 0; w < 8; w++) {
    k5a[w] = *(const float4*)(k5_w + w * 64 + h0);
    k5c[w] = *(const float4*)(k5_w + w * 64 + h0 + 4);
  }
  float kb5 = k5_b[s];
  float4 t3a = *(const float4*)(t3 + p * 4096 + b * 64 + h0);
  float4 t3b = *(const float4*)(t3 + p * 4096 + b * 64 + h0 + 4);
  float acc[32];
#pragma unroll
  for (int i = 0; i < 32; i++) acc[i] = 0.0f;
  int s0 = part_start[p], s1 = part_start[p + 1];
  int cnt = s1 - s0;
  if (cnt > 0) {
    const int2* pe = pe2 + s0;
    // --- prologue: current + next edge descriptors and operand loads ---
    int2 c0 = pe[0];
    int2 cN = (cnt > 1) ? pe[1] : c0;
    int rC = c0.y;
    float4 kbC0 = *(const float4*)(kb + c0.x * 64 + h0);
    float4 kbC1 = *(const float4*)(kb + c0.x * 64 + h0 + 4);
    float4 t4C0 = *(const float4*)(t4 + rC * 4096 + b * 64 + h0);
    float4 t4C1 = *(const float4*)(t4 + rC * 4096 + b * 64 + h0 + 4);
    float4 kbN0 = *(const float4*)(kb + cN.x * 64 + h0);
    float4 kbN1 = *(const float4*)(kb + cN.x * 64 + h0 + 4);
    float4 t4N0 = *(const float4*)(t4 + cN.y * 4096 + b * 64 + h0);
    float4 t4N1 = *(const float4*)(t4 + cN.y * 4096 + b * 64 + h0 + 4);
    for (int idx = 0; idx < cnt; idx++) {
      // descriptor 2 ahead: single independent load (no e->r chain)
      int i2 = idx + 2 < cnt ? idx + 2 : cnt - 1;
      int2 c2 = pe[i2];
      // x chunk A for current edge (consumed last)
      const float4* xp = (const float4*)(x + rC * 2048 + b * 32);
      float4 xa0 = xp[0], xa1 = xp[1], xa2 = xp[2], xa3 = xp[3];
      // kern + leaky(0.02) for this lane's 8 h
      float lk0, lk1, lk2, lk3, lk4, lk5, lk6, lk7, v;
      v = kbC0.x + t3a.x + t4C0.x; lk0 = v > 0.0f ? v : 0.02f * v;
      v = kbC0.y + t3a.y + t4C0.y; lk1 = v > 0.0f ? v : 0.02f * v;
      v = kbC0.z + t3a.z + t4C0.z; lk2 = v > 0.0f ? v : 0.02f * v;
      v = kbC0.w + t3a.w + t4C0.w; lk3 = v > 0.0f ? v : 0.02f * v;
      v = kbC1.x + t3b.x + t4C1.x; lk4 = v > 0.0f ? v : 0.02f * v;
      v = kbC1.y + t3b.y + t4C1.y; lk5 = v > 0.0f ? v : 0.02f * v;
      v = kbC1.z + t3b.z + t4C1.z; lk6 = v > 0.0f ? v : 0.02f * v;
      v = kbC1.w + t3b.w + t4C1.w; lk7 = v > 0.0f ? v : 0.02f * v;
      // x chunk B
      float4 xa4 = xp[4], xa5 = xp[5], xa6 = xp[6], xa7 = xp[7];
      // partial dot: pw[w] over this lane's 8 h (64 independent FMA)
      float pw[8];
#pragma unroll
      for (int w = 0; w < 8; w++)
        pw[w] = lk0 * k5a[w].x + lk1 * k5a[w].y + lk2 * k5a[w].z + lk3 * k5a[w].w +
                lk4 * k5c[w].x + lk5 * k5c[w].y + lk6 * k5c[w].z + lk7 * k5c[w].w;
      // 7-shfl reduce-scatter over the 8 s-lanes: lane s ends with full sum for w=s
      int b0 = s & 1, b1 = s & 2, b2 = s & 4;
      float q0 = (b0 ? pw[1] : pw[0]) + __shfl_xor(b0 ? pw[0] : pw[1], 1);
      float q1 = (b0 ? pw[3] : pw[2]) + __shfl_xor(b0 ? pw[2] : pw[3], 1);
      float q2 = (b0 ? pw[5] : pw[4]) + __shfl_xor(b0 ? pw[4] : pw[5], 1);
      float q3 = (b0 ? pw[7] : pw[6]) + __shfl_xor(b0 ? pw[6] : pw[7], 1);
      float u0 = (b1 ? q1 : q0) + __shfl_xor(b1 ? q0 : q1, 2);
      float u1 = (b1 ? q3 : q2) + __shfl_xor(b1 ? q2 : q3, 2);
      float fv = (b2 ? u1 : u0) + __shfl_xor(b2 ? u0 : u1, 4);
      float kv = fmaxf(fv + kb5, 0.0f);
      // rank-1 accumulate: acc[f] += kv * x[rC][b][f]  (32 FMA)
      acc[0]  += kv * xa0.x; acc[1]  += kv * xa0.y; acc[2]  += kv * xa0.z; acc[3]  += kv * xa0.w;
      acc[4]  += kv * xa1.x; acc[5]  += kv * xa1.y; acc[6]  += kv * xa1.z; acc[7]  += kv * xa1.w;
      acc[8]  += kv * xa2.x; acc[9]  += kv * xa2.y; acc[10] += kv * xa2.z; acc[11] += kv * xa2.w;
      acc[12] += kv * xa3.x; acc[13] += kv * xa3.y; acc[14] += kv * xa3.z; acc[15] += kv * xa3.w;
      acc[16] += kv * xa4.x; acc[17] += kv * xa4.y; acc[18] += kv * xa4.z; acc[19] += kv * xa4.w;
      acc[20] += kv * xa5.x; acc[21] += kv * xa5.y; acc[22] += kv * xa5.z; acc[23] += kv * xa5.w;
      acc[24] += kv * xa6.x; acc[25] += kv * xa6.y; acc[26] += kv * xa6.z; acc[27] += kv * xa6.w;
      acc[28] += kv * xa7.x; acc[29] += kv * xa7.y; acc[30] += kv * xa7.z; acc[31] += kv * xa7.w;
      // rotate double-buffer; issue loads for edge idx+2
      kbC0 = kbN0; kbC1 = kbN1; t4C0 = t4N0; t4C1 = t4N1;
      rC = cN.y;
      kbN0 = *(const float4*)(kb + c2.x * 64 + h0);
      kbN1 = *(const float4*)(kb + c2.x * 64 + h0 + 4);
      t4N0 = *(const float4*)(t4 + c2.y * 4096 + b * 64 + h0);
      t4N1 = *(const float4*)(t4 + c2.y * 4096 + b * 64 + h0 + 4);
      cN = c2;
    }
  }
  // store acc (fp32) to LDS: logical kcol = s*8+j, phys col = s*8 | ((j^s^b)&7)
#pragma unroll
  for (int j = 0; j < 8; j++) {
    int col = (s * 8) | ((j ^ s ^ b) & 7);
    *(float4*)(accS + b * 256 + col * 4) =
        make_float4(acc[4 * j], acc[4 * j + 1], acc[4 * j + 2], acc[4 * j + 3]);
  }
  __syncthreads();
  // epilogue: wave gq handles g in [gq*8, gq*8+8) for all 64 b (lane = b).
  // gc_w loads are wave-uniform (scalarizable); accS reads conflict-free (2-way).
  int gq = t >> 6, be = t & 63;
  const float* gwb = gc_w + gq * 8 * 256;
  float ac[8];
#pragma unroll
  for (int i = 0; i < 8; i++) ac[i] = 0.0f;
  for (int k4 = 0; k4 < 64; k4++) {
    int col = (k4 & 56) | ((k4 ^ (k4 >> 3) ^ be) & 7);
    float4 av = *(const float4*)(accS + be * 256 + col * 4);
#pragma unroll
    for (int i = 0; i < 8; i++) {
      float4 wv = *(const float4*)(gwb + i * 256 + k4 * 4);
      ac[i] += av.x * wv.x + av.y * wv.y + av.z * wv.z + av.w * wv.w;
    }
  }
  float* yp = yg + be * 16384 + p * 64 + gq * 8;
#pragma unroll
  for (int i = 0; i < 8; i++)
    yp[i] = fmaxf(ac[i] + gc_b[gq * 8 + i], 0.0f);
}

// r0 GEMM partials: grid 256 = kc (Kc=64). Block computes full 64b x 256rh tile
// for its k-chunk via outer product; writes part[kc][b][rh].
__global__ __launch_bounds__(256) void k_r0(const float* __restrict__ yg,
    const float* __restrict__ r0_w, float* __restrict__ part) {
  __shared__ float ygs[64 * 68];   // ygT[k][b], row stride 68
  __shared__ float wts[64 * 260];  // wT[k][rh], row stride 260
  int kc = blockIdx.x, t = threadIdx.x;
  int k0 = kc * 64;
  // stage wT: c = t>>4 selects k-group (store lanes spread 32 banks), rr = t&15
  {
    int c = t >> 4, rr = t & 15;
    for (int rd = 0; rd < 16; rd++) {
      int rh = rd * 16 + rr;
      float4 v = *(const float4*)(r0_w + rh * 16384 + k0 + c * 4);
      wts[(4 * c + 0) * 260 + rh] = v.x;
      wts[(4 * c + 1) * 260 + rh] = v.y;
      wts[(4 * c + 2) * 260 + rh] = v.z;
      wts[(4 * c + 3) * 260 + rh] = v.w;
    }
  }
  // stage ygT
  {
    int b = t >> 2, kq = t & 3;
    const float* src = yg + b * 16384 + k0 + kq * 16;
#pragma unroll
    for (int u = 0; u < 4; u++) {
      float4 v = *(const float4*)(src + u * 4);
      int kk = kq * 16 + u * 4;
      ygs[(kk + 0) * 68 + b] = v.x;
      ygs[(kk + 1) * 68 + b] = v.y;
      ygs[(kk + 2) * 68 + b] = v.z;
      ygs[(kk + 3) * 68 + b] = v.w;
    }
  }
  __syncthreads();
  int lane = t & 63, wv = t >> 6;
  int b8 = lane & 7, r8 = lane >> 3;
  const float* yp = ygs + b8 * 8;
  const float* wp = wts + wv * 64 + r8 * 8;
  float acc[8][8];
#pragma unroll
  for (int i = 0; i < 8; i++)
#pragma unroll
    for (int j = 0; j < 8; j++) acc[i][j] = 0.0f;
#pragma unroll 2
  for (int k = 0; k < 64; k++) {
    float4 ya = *(const float4*)(yp + k * 68);
    float4 yb = *(const float4*)(yp + k * 68 + 4);
    float4 wa = *(const float4*)(wp + k * 260);
    float4 wb = *(const float4*)(wp + k * 260 + 4);
    float yv[8] = {ya.x, ya.y, ya.z, ya.w, yb.x, yb.y, yb.z, yb.w};
    float wr[8] = {wa.x, wa.y, wa.z, wa.w, wb.x, wb.y, wb.z, wb.w};
#pragma unroll
    for (int i = 0; i < 8; i++)
#pragma unroll
      for (int j = 0; j < 8; j++) acc[i][j] += yv[i] * wr[j];
  }
  float* pb = part + kc * 16384 + wv * 64 + r8 * 8;
#pragma unroll
  for (int i = 0; i < 8; i++) {
    float4 s0 = make_float4(acc[i][0], acc[i][1], acc[i][2], acc[i][3]);
    float4 s1 = make_float4(acc[i][4], acc[i][5], acc[i][6], acc[i][7]);
    float* pp = pb + (b8 * 8 + i) * 256;
    *(float4*)pp = s0;
    *(float4*)(pp + 4) = s1;
  }
}

// Reduce partials: grid 256 = (kq 4) x (oq 64). hbuf[o] += sum_{kc in kq} part[kc][o]
__global__ __launch_bounds__(256) void k_r0red(const float* __restrict__ part,
    float* __restrict__ hbuf) {
  int blk = blockIdx.x;
  int oq = blk & 63, kq = blk >> 6;
  int o = oq * 256 + threadIdx.x;
  float s = 0.0f;
  const float* pp = part + kq * 64 * 16384 + o;
#pragma unroll 8
  for (int kc = 0; kc < 64; kc++) s += pp[kc * 16384];
  atomicAdd(&hbuf[o], s);
}

// grid 256 = (bb, pq): wt for 64 p's, partial res over those p's -> res4[pq][b][g]
__global__ __launch_bounds__(256) void k_wt_res(const float* __restrict__ hbuf,
    const float* __restrict__ r3_w, const float* __restrict__ r3_b,
    const float* __restrict__ yg, float* __restrict__ res4) {
  __shared__ float hs[256];
  __shared__ float wts[64];
  __shared__ float red[256];
  int blk = blockIdx.x;
  int bb = blk >> 2, pq = blk & 3;
  int t = threadIdx.x;
  float hv = hbuf[bb * 256 + t];
  hs[t] = hv > 0.0f ? hv : 0.01f * hv;
  __syncthreads();
  int pl = t >> 2, c = t & 3;
  int pp = pq * 64 + pl;
  const float4* wrow = (const float4*)(r3_w + pp * 256 + c * 64);
  const float4* h4 = (const float4*)(hs) + c * 16;
  float a = 0.0f;
#pragma unroll
  for (int j = 0; j < 16; j++) {
    float4 w4 = wrow[j], hh = h4[j];
    a += hh.x * w4.x + hh.y * w4.y + hh.z * w4.z + hh.w * w4.w;
  }
  a += __shfl_xor(a, 1);
  a += __shfl_xor(a, 2);
  if (c == 0) wts[pl] = fmaxf(a + r3_b[pp], 0.0f);
  __syncthreads();
  int g = t & 63, ch = t >> 6;
  float r = 0.0f;
  const float* ygp = yg + bb * 16384 + pq * 4096 + g;
#pragma unroll
  for (int pi = 0; pi < 16; pi++) {
    int pl2 = ch * 16 + pi;
    r += wts[pl2] * ygp[pl2 * 64];
  }
  red[t] = r;
  __syncthreads();
  if (t < 64)
    res4[pq * 4096 + bb * 64 + t] = red[t] + red[t + 64] + red[t + 128] + red[t + 192];
}

// z = elu([sum(res4), x2] @ l1_w^T + l1_b); out = z @ l3_w^T + l3_b
__global__ __launch_bounds__(128) void k_final(const float* __restrict__ res4,
    const float* __restrict__ x2, const float* __restrict__ l1_w,
    const float* __restrict__ l1_b, const float* __restrict__ l3_w,
    const float* __restrict__ l3_b, float* __restrict__ out) {
  __shared__ float zs[128];
  int bb = blockIdx.x, t = threadIdx.x;
  float acc = l1_b[t];
  const float* wrow = l1_w + t * 72;
  const float* rr = res4 + bb * 64;
#pragma unroll 8
  for (int j = 0; j < 64; j++) {
    float rv = rr[j] + rr[4096 + j] + rr[8192 + j] + rr[12288 + j];
    acc += rv * wrow[j];
  }
  const float* xr = x2 + bb * 8;
#pragma unroll
  for (int j = 0; j < 8; j++) acc += xr[j] * wrow[64 + j];
  zs[t] = acc > 0.0f ? acc : expm1f(acc);
  __syncthreads();
  if (t < 9) {
    float o = l3_b[t];
    const float* w3 = l3_w + t * 128;
    for (int j = 0; j < 128; j++) o += zs[j] * w3[j];
    out[bb * 9 + t] = o;
  }
}

extern "C" void kernel_launch(void* const* d_in, const int* in_sizes, int n_in,
                              void* d_out, int out_size, void* d_ws, size_t ws_size,
                              hipStream_t stream) {
  (void)in_sizes; (void)n_in; (void)out_size; (void)ws_size;
  const float* x1     = (const float*)d_in[0];
  const float* x2     = (const float*)d_in[1];
  const float* conv_w = (const float*)d_in[2];
  const float* conv_b = (const float*)d_in[3];
  const float* k1_w   = (const float*)d_in[4];
  const float* k1_b   = (const float*)d_in[5];
  const float* k2_w   = (const float*)d_in[6];
  const float* k3_w   = (const float*)d_in[7];
  const float* k4_w   = (const float*)d_in[8];
  const float* k5_w   = (const float*)d_in[9];
  const float* k5_b   = (const float*)d_in[10];
  const float* gc_w   = (const float*)d_in[11];
  const float* gc_b   = (const float*)d_in[12];
  const float* r0_w   = (const float*)d_in[13];
  const float* r1_w   = (const float*)d_in[14];
  const float* r1_b   = (const float*)d_in[15];
  const float* r2_w   = (const float*)d_in[16];
  const float* r3_w   = (const float*)d_in[17];
  const float* r3_b   = (const float*)d_in[18];
  const float* l1_w   = (const float*)d_in[19];
  const float* l1_b   = (const float*)d_in[20];
  const float* l3_w   = (const float*)d_in[21];
  const float* l3_b   = (const float*)d_in[22];
  const float* ef     = (const float*)d_in[23];
  const float* linc   = (const float*)d_in[24];
  const float* rinc   = (const float*)d_in[25];
  const float* cap    = (const float*)d_in[26];
  const int*   pidx   = (const int*)d_in[27];
  float* out = (float*)d_out;

  float* ws   = (float*)d_ws;
  float* xbuf = ws + X_OFF;
  float* t4   = ws + T4_OFF;
  float* t3   = ws + T3_OFF;
  float* kb   = ws + KB_OFF;
  float* yg   = ws + YG_OFF;
  float* hbuf = ws + HB_OFF;
  float* res4 = ws + RES_OFF;
  float* part = ws + X_OFF;   // aliases x/t4/t3/kb (dead after k_eagg)
  int* ib = (int*)(ws + INT_OFF);
  int* lidx = ib;
  int* ridx = ib + 4096;
  int* part_start = ib + 8192;
  int2* pe2 = (int2*)(ib + 8704);   // 4096 int2 = 8192 ints

  hipLaunchKernelGGL(k_decode, dim3(3072), dim3(256), 0, stream, linc, rinc, lidx, ridx);
  hipLaunchKernelGGL(k_lists, dim3(1), dim3(1024), 0, stream, lidx, ridx, part_start, pe2);
  hipLaunchKernelGGL(k_conv, dim3(512), dim3(256), 0, stream, x1, conv_w, conv_b, xbuf);
  hipLaunchKernelGGL(k_prep, dim3(1856), dim3(256), 0, stream,
                     xbuf, pidx, k3_w, k4_w, x2, k2_w, ef, k1_w, k1_b,
                     r1_w, r1_b, r2_w, cap, t4, t3, kb, hbuf);
  hipLaunchKernelGGL(k_eagg, dim3(256), dim3(512), 0, stream,
                     xbuf, kb, t3, t4, k5_w, k5_b, pe2, part_start,
                     gc_w, gc_b, yg);
  hipLaunchKernelGGL(k_r0, dim3(256), dim3(256), 0, stream, yg, r0_w, part);
  hipLaunchKernelGGL(k_r0red, dim3(256), dim3(256), 0, stream, part, hbuf);
  hipLaunchKernelGGL(k_wt_res, dim3(256), dim3(256), 0, stream, hbuf, r3_w, r3_b, yg, res4);
  hipLaunchKernelGGL(k_final, dim3(64), dim3(128), 0, stream,
                     res4, x2, l1_w, l1_b, l3_w, l3_b, out);
}

// Round 4
// 258.714 us; speedup vs baseline: 1.0741x; 1.0741x over previous
//
#include <hip/hip_runtime.h>
#include <math.h>

#define B_ 64
#define N_ 512
#define P_ 256
#define E_ 4096
#define F_ 32
#define H_ 64
#define W_ 8
#define G_ 64
#define RH_ 256

// ---- workspace layout (float offsets) ----
#define X_OFF   0
#define T4_OFF  (X_OFF + N_*B_*F_)       // x:  [n][b][f]
#define T3_OFF  (T4_OFF + N_*B_*H_)      // t4: [n][b][h] (t2 folded in)
#define KB_OFF  (T3_OFF + P_*B_*H_)      // t3: [p][b][h]
#define KW_OFF  (KB_OFF + E_*H_)         // kb: [e][h]
#define YG_OFF  (KW_OFF + E_*B_*W_)      // (kw slot unused now, kept for layout stability)
#define HB_OFF  (YG_OFF + B_*P_*G_)      // yg: [b][p*64+g]
#define RES_OFF (HB_OFF + B_*RH_)        // hbuf: [b][rh]
#define INT_OFF (RES_OFF + 4*B_*G_)      // res4: [pq][b][g]
// int region at INT_OFF: lidx[4096] | ridx[4096] | part_start[512] | pe2[4096 int2]
// r0 partials (256*16384 floats = 16 MB) alias X_OFF.. (x/t4/t3/kb dead after k_eagg)

// ---------------------------------------------------------------------------
// Fused: blocks [0,3072) decode linc/rinc -> lidx/ridx; blocks [3072,3584) conv.
__global__ __launch_bounds__(256) void k_dc(
    const float* __restrict__ linc, const float* __restrict__ rinc,
    int* __restrict__ lidx, int* __restrict__ ridx,
    const float* __restrict__ x1, const float* __restrict__ conv_w,
    const float* __restrict__ conv_b, float* __restrict__ x) {
  __shared__ float wsm[32 * 132];
  __shared__ float xsm[8192];
  int blk = blockIdx.x, t = threadIdx.x;
  if (blk < 3072) {
    int i4 = blk * 256 + t;
    const int L4 = (P_ * E_) / 4;  // 262144
    if (i4 < L4) {
      float4 v = ((const float4*)linc)[i4];
      int i = i4 * 4;
      int p = i >> 12, e = i & 4095;
      if (v.x != 0.0f) lidx[e]     = p;
      if (v.y != 0.0f) lidx[e + 1] = p;
      if (v.z != 0.0f) lidx[e + 2] = p;
      if (v.w != 0.0f) lidx[e + 3] = p;
    } else {
      int j4 = i4 - L4;
      float4 v = ((const float4*)rinc)[j4];
      int j = j4 * 4;
      int e = j >> 9, n = j & 511;
      if (v.x != 0.0f) ridx[e] = n;
      if (v.y != 0.0f) ridx[e] = n + 1;
      if (v.z != 0.0f) ridx[e] = n + 2;
      if (v.w != 0.0f) ridx[e] = n + 3;
    }
    return;
  }
  // ---- grouped conv (K=16, VALID, 1 out pos) + bias + relu -> x[n][b][f] ----
  int n = blk - 3072;
  for (int i = t; i < 1024; i += 256) {
    int f = i >> 5, j = i & 31;
    ((float4*)wsm)[f * 33 + j] = ((const float4*)(conv_w + n * 4096))[i];
  }
  for (int i = t; i < 2048; i += 256) {
    int b = i >> 5, j = i & 31;
    ((float4*)xsm)[i] = ((const float4*)(x1 + b * 65536 + n * 128))[j];
  }
  __syncthreads();
  int f = t & 31, bq = t >> 5;
  float cb = conv_b[n * 32 + f];
  float acc[8];
#pragma unroll
  for (int bi = 0; bi < 8; bi++) acc[bi] = cb;
  const float4* wf4 = (const float4*)wsm + f * 33;
  const float4* xb4 = (const float4*)xsm + bq * 256;
#pragma unroll 4
  for (int k4 = 0; k4 < 32; k4++) {
    float4 wv = wf4[k4];
#pragma unroll
    for (int bi = 0; bi < 8; bi++) {
      float4 xv = xb4[bi * 32 + k4];
      acc[bi] += wv.x * xv.x + wv.y * xv.y + wv.z * xv.z + wv.w * xv.w;
    }
  }
#pragma unroll
  for (int bi = 0; bi < 8; bi++) {
    int b = bq * 8 + bi;
    x[n * 2048 + b * 32 + f] = fmaxf(acc[bi], 0.0f);
  }
}

// blocks [0,512): t4[n][b][h] = x[n]@k4_w^T + x2@k2_w^T
// blocks [512,768): t3[p][b][h] = x[pidx[p]]@k3_w^T
// blocks [768,1792): kb[e][h] = ef[e,:8]@k1_w^T + k1_b
// blocks [1792,1856): hbuf[b][rh] = x2@r1_w^T + r1_b + cap@r2_w^T
// block 1856: counting-sort edges by partition -> part_start, pe2 (e,r) pairs
__global__ __launch_bounds__(256) void k_prep(
    const float* __restrict__ x, const int* __restrict__ pidx,
    const float* __restrict__ k3_w, const float* __restrict__ k4_w,
    const float* __restrict__ x2, const float* __restrict__ k2_w,
    const float* __restrict__ ef, const float* __restrict__ k1_w,
    const float* __restrict__ k1_b,
    const float* __restrict__ r1_w, const float* __restrict__ r1_b,
    const float* __restrict__ r2_w, const float* __restrict__ cap,
    const int* __restrict__ lidx, const int* __restrict__ ridx,
    float* __restrict__ t4, float* __restrict__ t3, float* __restrict__ kb,
    float* __restrict__ hbuf, int* __restrict__ part_start,
    int2* __restrict__ pe2) {
  __shared__ float xsh[2048];
  __shared__ float wsh[64 * 36];
  __shared__ float x2s[512];
  __shared__ float k2s[512];
  __shared__ int cnt[256];
  __shared__ int buf[256];
  __shared__ int cur[256];
  int blk = blockIdx.x, t = threadIdx.x;
  if (blk < 768) {
    bool isT4 = blk < 512;
    int n = isT4 ? blk : pidx[blk - 512];
    const float* wmat = isT4 ? k4_w : k3_w;
    float* outp = isT4 ? (t4 + blk * 4096) : (t3 + (blk - 512) * 4096);
    for (int i = t; i < 512; i += 256) {
      ((float4*)xsh)[i] = ((const float4*)(x + n * 2048))[i];
      int h = i >> 3, j = i & 7;
      ((float4*)wsh)[h * 9 + j] = ((const float4*)wmat)[i];
    }
    if (isT4) {
      for (int i = t; i < 128; i += 256) {
        ((float4*)x2s)[i] = ((const float4*)x2)[i];
        ((float4*)k2s)[i] = ((const float4*)k2_w)[i];
      }
    }
    __syncthreads();
    int h = t & 63, bq = t >> 6;
    float wreg[32];
#pragma unroll
    for (int j = 0; j < 8; j++) {
      float4 v = ((float4*)wsh)[h * 9 + j];
      wreg[4 * j] = v.x; wreg[4 * j + 1] = v.y; wreg[4 * j + 2] = v.z; wreg[4 * j + 3] = v.w;
    }
    float w2[8];
    if (isT4) {
      float4 u = ((float4*)k2s)[h * 2], v = ((float4*)k2s)[h * 2 + 1];
      w2[0] = u.x; w2[1] = u.y; w2[2] = u.z; w2[3] = u.w;
      w2[4] = v.x; w2[5] = v.y; w2[6] = v.z; w2[7] = v.w;
    }
    for (int bi = 0; bi < 16; bi++) {
      int b = bq * 16 + bi;
      float acc = 0.0f;
#pragma unroll
      for (int j = 0; j < 8; j++) {
        float4 xv = ((float4*)xsh)[b * 8 + j];
        acc += xv.x * wreg[4 * j] + xv.y * wreg[4 * j + 1] +
               xv.z * wreg[4 * j + 2] + xv.w * wreg[4 * j + 3];
      }
      if (isT4) {
        float4 u = ((float4*)x2s)[b * 2], v = ((float4*)x2s)[b * 2 + 1];
        acc += u.x * w2[0] + u.y * w2[1] + u.z * w2[2] + u.w * w2[3] +
               v.x * w2[4] + v.y * w2[5] + v.z * w2[6] + v.w * w2[7];
      }
      outp[b * 64 + h] = acc;
    }
  } else if (blk < 1792) {
    int o = (blk - 768) * 256 + t;
    int e = o >> 6, h = o & 63;
    float acc = k1_b[h];
    const float* er = ef + e * 9;
    const float* kr = k1_w + h * 8;
#pragma unroll
    for (int d = 0; d < 8; d++) acc += er[d] * kr[d];
    kb[o] = acc;
  } else if (blk < 1856) {
    int o = (blk - 1792) * 256 + t;
    int rh = o & 255;
    float acc = r1_b[rh];
    const float* xr = x2 + (o >> 8) * 8;
    const float* rr = r1_w + rh * 8;
#pragma unroll
    for (int d = 0; d < 8; d++) acc += xr[d] * rr[d];
    const float* r2r = r2_w + rh * 256;
    for (int p4 = 0; p4 < 64; p4++) {
      float4 cv = ((const float4*)cap)[p4];
      float4 rv = ((const float4*)r2r)[p4];
      acc += cv.x * rv.x + cv.y * rv.y + cv.z * rv.z + cv.w * rv.w;
    }
    hbuf[o] = acc;
  } else {
    // ---- counting sort (single block, 256 threads) ----
    cnt[t] = 0;
    __syncthreads();
    for (int e = t; e < E_; e += 256) atomicAdd(&cnt[lidx[e]], 1);
    __syncthreads();
    buf[t] = cnt[t];
    __syncthreads();
    for (int off = 1; off < 256; off <<= 1) {
      int add = (t >= off) ? buf[t - off] : 0;
      __syncthreads();
      buf[t] += add;
      __syncthreads();
    }
    part_start[t + 1] = buf[t];
    if (t == 0) part_start[0] = 0;
    cur[t] = buf[t] - cnt[t];
    __syncthreads();
    for (int e = t; e < E_; e += 256) {
      int p = lidx[e];
      int pos = atomicAdd(&cur[p], 1);
      pe2[pos] = make_int2(e, ridx[e]);
    }
  }
}

// Fused edge-MLP + aggregation + gc GEMM, one block (512 thr) per partition.
// Two edge-slots (slot = t>>8): slot0 even edges, slot1 odd edges -> serial
// edge chain halved, 8 waves/CU. Per-slot laneing identical to the proven
// round-0 shape: s = t&3 owns h [s*16,s*16+16) and w-pair {2s,2s+1}; b = batch.
// k5t + t3s in LDS (the shape the allocator handles honestly, 132 VGPR).
// Slots merge through fp32 accS [64][128] in two f-half phases (exact, no bf16),
// then the gc GEMM epilogue (8 waves x 8 g) reads accS with the same swizzle.
__global__ __launch_bounds__(512) void k_eagg(
    const float* __restrict__ x, const float* __restrict__ kb,
    const float* __restrict__ t3, const float* __restrict__ t4,
    const float* __restrict__ k5_w, const float* __restrict__ k5_b,
    const int2* __restrict__ pe2, const int* __restrict__ part_start,
    const float* __restrict__ gc_w, const float* __restrict__ gc_b,
    float* __restrict__ yg) {
  __shared__ float t3s[64 * 68];   // [b][h], stride 68 (bank-spread)
  __shared__ float k5t[4 * 520];   // s-replicated [h][w]
  __shared__ float accS[64 * 128]; // fp32 [b][f-half k], XOR-swizzled (32 KB)
  int p = blockIdx.x, t = threadIdx.x;
  int slot = t >> 8;
  int ts = t & 255;
  int s = ts & 3, b = ts >> 2;
  // stage k5t (512 entries, one per thread) and t3s
  {
    int h = t >> 3, w = t & 7;
    float v = k5_w[w * 64 + h];
#pragma unroll
    for (int qq = 0; qq < 4; qq++) k5t[qq * 520 + t] = v;
  }
  for (int i4 = t; i4 < 1024; i4 += 512) {
    float4 v = ((const float4*)(t3 + p * 4096))[i4];
    *(float4*)(t3s + (i4 >> 4) * 68 + (i4 & 15) * 4) = v;
  }
  __syncthreads();
  const float* kq = k5t + s * 520 + s * 128;  // rows h = s*16..s*16+15
  float kb5_0 = k5_b[2 * s], kb5_1 = k5_b[2 * s + 1];
  const float4* t3p = (const float4*)(t3s + b * 68 + s * 16);
  float acc[64];
#pragma unroll
  for (int j = 0; j < 64; j++) acc[j] = 0.0f;
  int s0 = part_start[p], s1 = part_start[p + 1];
  int idx0 = s0 + slot;
  int2 c = make_int2(0, 0);
  if (idx0 < s1) c = pe2[idx0];
  for (int idx = idx0; idx < s1; idx += 2) {
    int n2 = idx + 2;
    int2 cn = (n2 < s1) ? pe2[n2] : c;
    int e = c.x, r = c.y;
    // issue x-row loads early (independent of kern math)
    const float4* xp = (const float4*)(x + r * 2048 + b * 32);
    float4 xv0 = xp[0], xv1 = xp[1], xv2 = xp[2], xv3 = xp[3];
    float4 xv4 = xp[4], xv5 = xp[5], xv6 = xp[6], xv7 = xp[7];
    const float4* kb4 = (const float4*)(kb + e * 64 + s * 16);
    const float4* t44 = (const float4*)(t4 + r * 4096 + b * 64 + s * 16);
    float lk[16];
#pragma unroll
    for (int j4 = 0; j4 < 4; j4++) {
      float4 a = kb4[j4], cc = t3p[j4], d = t44[j4];
      float v;
      v = a.x + cc.x + d.x; lk[j4 * 4 + 0] = v > 0.0f ? v : 0.02f * v;
      v = a.y + cc.y + d.y; lk[j4 * 4 + 1] = v > 0.0f ? v : 0.02f * v;
      v = a.z + cc.z + d.z; lk[j4 * 4 + 2] = v > 0.0f ? v : 0.02f * v;
      v = a.w + cc.w + d.w; lk[j4 * 4 + 3] = v > 0.0f ? v : 0.02f * v;
    }
    float pw[8] = {0, 0, 0, 0, 0, 0, 0, 0};
#pragma unroll
    for (int j = 0; j < 16; j++) {
      float4 u = *(const float4*)(kq + j * 8);
      float4 v = *(const float4*)(kq + j * 8 + 4);
      float l = lk[j];
      pw[0] += l * u.x; pw[1] += l * u.y; pw[2] += l * u.z; pw[3] += l * u.w;
      pw[4] += l * v.x; pw[5] += l * v.y; pw[6] += l * v.z; pw[7] += l * v.w;
    }
#pragma unroll
    for (int w = 0; w < 8; w++) {  // reduce over the 4 s-lanes
      pw[w] += __shfl_xor(pw[w], 1);
      pw[w] += __shfl_xor(pw[w], 2);
    }
    float kv0 = fmaxf(pw[2 * s] + kb5_0, 0.0f);
    float kv1 = fmaxf(pw[2 * s + 1] + kb5_1, 0.0f);
    float xa[32];
    xa[0] = xv0.x; xa[1] = xv0.y; xa[2] = xv0.z; xa[3] = xv0.w;
    xa[4] = xv1.x; xa[5] = xv1.y; xa[6] = xv1.z; xa[7] = xv1.w;
    xa[8] = xv2.x; xa[9] = xv2.y; xa[10] = xv2.z; xa[11] = xv2.w;
    xa[12] = xv3.x; xa[13] = xv3.y; xa[14] = xv3.z; xa[15] = xv3.w;
    xa[16] = xv4.x; xa[17] = xv4.y; xa[18] = xv4.z; xa[19] = xv4.w;
    xa[20] = xv5.x; xa[21] = xv5.y; xa[22] = xv5.z; xa[23] = xv5.w;
    xa[24] = xv6.x; xa[25] = xv6.y; xa[26] = xv6.z; xa[27] = xv6.w;
    xa[28] = xv7.x; xa[29] = xv7.y; xa[30] = xv7.z; xa[31] = xv7.w;
#pragma unroll
    for (int j = 0; j < 32; j++) acc[j] += kv0 * xa[j];
#pragma unroll
    for (int j = 0; j < 32; j++) acc[32 + j] += kv1 * xa[j];
    c = cn;
  }
  // ---- slot merge + gc GEMM in two f-half phases (fp32 exact) ----
  // thread's k: w = 2s+w2, f: acc[w2*32 + f]. Phase h covers f in [h*16,h*16+16).
  // khalf4 = 8s + 4*w2 + fr4 (float4 col in half-buffer); swizzle:
  // phys4 = (khalf4 & 24) | ((khalf4 ^ (khalf4>>3) ^ row) & 7)  [khalf4>>3 == s]
  int gq = t >> 6, be = t & 63;
  const float* gwb = gc_w + gq * 8 * 256;
  float ac[8];
#pragma unroll
  for (int i = 0; i < 8; i++) ac[i] = 0.0f;
#pragma unroll
  for (int h = 0; h < 2; h++) {
    if (h) __syncthreads();  // protect accS from overwrite while phase-0 reads finish
    if (slot == 0) {
#pragma unroll
      for (int w2 = 0; w2 < 2; w2++)
#pragma unroll
        for (int fr4 = 0; fr4 < 4; fr4++) {
          int khalf4 = 8 * s + 4 * w2 + fr4;
          int phys4 = (khalf4 & 24) | ((khalf4 ^ s ^ b) & 7);
          int j = 32 * w2 + 16 * h + 4 * fr4;
          *(float4*)(accS + b * 128 + phys4 * 4) =
              make_float4(acc[j], acc[j + 1], acc[j + 2], acc[j + 3]);
        }
    }
    __syncthreads();
    if (slot == 1) {
#pragma unroll
      for (int w2 = 0; w2 < 2; w2++)
#pragma unroll
        for (int fr4 = 0; fr4 < 4; fr4++) {
          int khalf4 = 8 * s + 4 * w2 + fr4;
          int phys4 = (khalf4 & 24) | ((khalf4 ^ s ^ b) & 7);
          int j = 32 * w2 + 16 * h + 4 * fr4;
          float4* ptr = (float4*)(accS + b * 128 + phys4 * 4);
          float4 o = *ptr;
          o.x += acc[j]; o.y += acc[j + 1]; o.z += acc[j + 2]; o.w += acc[j + 3];
          *ptr = o;
        }
    }
    __syncthreads();
    // epilogue partial over this f-half: all 8 waves, wave gq -> g [gq*8,gq*8+8)
    for (int k4h = 0; k4h < 32; k4h++) {
      int phys4 = (k4h & 24) | ((k4h ^ (k4h >> 3) ^ be) & 7);
      float4 av = *(const float4*)(accS + be * 128 + phys4 * 4);
      int w = k4h >> 2, fr4 = k4h & 3;
      int k4g = w * 8 + h * 4 + fr4;  // global float4 col: k = w*32 + h*16 + fr
#pragma unroll
      for (int i = 0; i < 8; i++) {
        float4 wv = *(const float4*)(gwb + i * 256 + k4g * 4);
        ac[i] += av.x * wv.x + av.y * wv.y + av.z * wv.z + av.w * wv.w;
      }
    }
  }
  float* yp = yg + be * 16384 + p * 64 + gq * 8;
#pragma unroll
  for (int i = 0; i < 8; i++)
    yp[i] = fmaxf(ac[i] + gc_b[gq * 8 + i], 0.0f);
}

// r0 GEMM partials: grid 256 = kc (Kc=64). Block computes full 64b x 256rh tile
// for its k-chunk via outer product; writes part[kc][b][rh].
__global__ __launch_bounds__(256) void k_r0(const float* __restrict__ yg,
    const float* __restrict__ r0_w, float* __restrict__ part) {
  __shared__ float ygs[64 * 68];   // ygT[k][b], row stride 68
  __shared__ float wts[64 * 260];  // wT[k][rh], row stride 260
  int kc = blockIdx.x, t = threadIdx.x;
  int k0 = kc * 64;
  // stage wT: c = t>>4 selects k-group (store lanes spread 32 banks), rr = t&15
  {
    int c = t >> 4, rr = t & 15;
    for (int rd = 0; rd < 16; rd++) {
      int rh = rd * 16 + rr;
      float4 v = *(const float4*)(r0_w + rh * 16384 + k0 + c * 4);
      wts[(4 * c + 0) * 260 + rh] = v.x;
      wts[(4 * c + 1) * 260 + rh] = v.y;
      wts[(4 * c + 2) * 260 + rh] = v.z;
      wts[(4 * c + 3) * 260 + rh] = v.w;
    }
  }
  // stage ygT
  {
    int b = t >> 2, kq = t & 3;
    const float* src = yg + b * 16384 + k0 + kq * 16;
#pragma unroll
    for (int u = 0; u < 4; u++) {
      float4 v = *(const float4*)(src + u * 4);
      int kk = kq * 16 + u * 4;
      ygs[(kk + 0) * 68 + b] = v.x;
      ygs[(kk + 1) * 68 + b] = v.y;
      ygs[(kk + 2) * 68 + b] = v.z;
      ygs[(kk + 3) * 68 + b] = v.w;
    }
  }
  __syncthreads();
  int lane = t & 63, wv = t >> 6;
  int b8 = lane & 7, r8 = lane >> 3;
  const float* yp = ygs + b8 * 8;
  const float* wp = wts + wv * 64 + r8 * 8;
  float acc[8][8];
#pragma unroll
  for (int i = 0; i < 8; i++)
#pragma unroll
    for (int j = 0; j < 8; j++) acc[i][j] = 0.0f;
#pragma unroll 2
  for (int k = 0; k < 64; k++) {
    float4 ya = *(const float4*)(yp + k * 68);
    float4 yb = *(const float4*)(yp + k * 68 + 4);
    float4 wa = *(const float4*)(wp + k * 260);
    float4 wb = *(const float4*)(wp + k * 260 + 4);
    float yv[8] = {ya.x, ya.y, ya.z, ya.w, yb.x, yb.y, yb.z, yb.w};
    float wr[8] = {wa.x, wa.y, wa.z, wa.w, wb.x, wb.y, wb.z, wb.w};
#pragma unroll
    for (int i = 0; i < 8; i++)
#pragma unroll
      for (int j = 0; j < 8; j++) acc[i][j] += yv[i] * wr[j];
  }
  float* pb = part + kc * 16384 + wv * 64 + r8 * 8;
#pragma unroll
  for (int i = 0; i < 8; i++) {
    float4 s0 = make_float4(acc[i][0], acc[i][1], acc[i][2], acc[i][3]);
    float4 s1 = make_float4(acc[i][4], acc[i][5], acc[i][6], acc[i][7]);
    float* pp = pb + (b8 * 8 + i) * 256;
    *(float4*)pp = s0;
    *(float4*)(pp + 4) = s1;
  }
}

// Reduce partials: grid 256 = (kq 4) x (oq 64). hbuf[o] += sum_{kc in kq} part[kc][o]
__global__ __launch_bounds__(256) void k_r0red(const float* __restrict__ part,
    float* __restrict__ hbuf) {
  int blk = blockIdx.x;
  int oq = blk & 63, kq = blk >> 6;
  int o = oq * 256 + threadIdx.x;
  float s = 0.0f;
  const float* pp = part + kq * 64 * 16384 + o;
#pragma unroll 8
  for (int kc = 0; kc < 64; kc++) s += pp[kc * 16384];
  atomicAdd(&hbuf[o], s);
}

// grid 256 = (bb, pq): wt for 64 p's, partial res over those p's -> res4[pq][b][g]
__global__ __launch_bounds__(256) void k_wt_res(const float* __restrict__ hbuf,
    const float* __restrict__ r3_w, const float* __restrict__ r3_b,
    const float* __restrict__ yg, float* __restrict__ res4) {
  __shared__ float hs[256];
  __shared__ float wts[64];
  __shared__ float red[256];
  int blk = blockIdx.x;
  int bb = blk >> 2, pq = blk & 3;
  int t = threadIdx.x;
  float hv = hbuf[bb * 256 + t];
  hs[t] = hv > 0.0f ? hv : 0.01f * hv;
  __syncthreads();
  int pl = t >> 2, c = t & 3;
  int pp = pq * 64 + pl;
  const float4* wrow = (const float4*)(r3_w + pp * 256 + c * 64);
  const float4* h4 = (const float4*)(hs) + c * 16;
  float a = 0.0f;
#pragma unroll
  for (int j = 0; j < 16; j++) {
    float4 w4 = wrow[j], hh = h4[j];
    a += hh.x * w4.x + hh.y * w4.y + hh.z * w4.z + hh.w * w4.w;
  }
  a += __shfl_xor(a, 1);
  a += __shfl_xor(a, 2);
  if (c == 0) wts[pl] = fmaxf(a + r3_b[pp], 0.0f);
  __syncthreads();
  int g = t & 63, ch = t >> 6;
  float r = 0.0f;
  const float* ygp = yg + bb * 16384 + pq * 4096 + g;
#pragma unroll
  for (int pi = 0; pi < 16; pi++) {
    int pl2 = ch * 16 + pi;
    r += wts[pl2] * ygp[pl2 * 64];
  }
  red[t] = r;
  __syncthreads();
  if (t < 64)
    res4[pq * 4096 + bb * 64 + t] = red[t] + red[t + 64] + red[t + 128] + red[t + 192];
}

// z = elu([sum(res4), x2] @ l1_w^T + l1_b); out = z @ l3_w^T + l3_b
__global__ __launch_bounds__(128) void k_final(const float* __restrict__ res4,
    const float* __restrict__ x2, const float* __restrict__ l1_w,
    const float* __restrict__ l1_b, const float* __restrict__ l3_w,
    const float* __restrict__ l3_b, float* __restrict__ out) {
  __shared__ float zs[128];
  int bb = blockIdx.x, t = threadIdx.x;
  float acc = l1_b[t];
  const float* wrow = l1_w + t * 72;
  const float* rr = res4 + bb * 64;
#pragma unroll 8
  for (int j = 0; j < 64; j++) {
    float rv = rr[j] + rr[4096 + j] + rr[8192 + j] + rr[12288 + j];
    acc += rv * wrow[j];
  }
  const float* xr = x2 + bb * 8;
#pragma unroll
  for (int j = 0; j < 8; j++) acc += xr[j] * wrow[64 + j];
  zs[t] = acc > 0.0f ? acc : expm1f(acc);
  __syncthreads();
  if (t < 9) {
    float o = l3_b[t];
    const float* w3 = l3_w + t * 128;
    for (int j = 0; j < 128; j++) o += zs[j] * w3[j];
    out[bb * 9 + t] = o;
  }
}

extern "C" void kernel_launch(void* const* d_in, const int* in_sizes, int n_in,
                              void* d_out, int out_size, void* d_ws, size_t ws_size,
                              hipStream_t stream) {
  (void)in_sizes; (void)n_in; (void)out_size; (void)ws_size;
  const float* x1     = (const float*)d_in[0];
  const float* x2     = (const float*)d_in[1];
  const float* conv_w = (const float*)d_in[2];
  const float* conv_b = (const float*)d_in[3];
  const float* k1_w   = (const float*)d_in[4];
  const float* k1_b   = (const float*)d_in[5];
  const float* k2_w   = (const float*)d_in[6];
  const float* k3_w   = (const float*)d_in[7];
  const float* k4_w   = (const float*)d_in[8];
  const float* k5_w   = (const float*)d_in[9];
  const float* k5_b   = (const float*)d_in[10];
  const float* gc_w   = (const float*)d_in[11];
  const float* gc_b   = (const float*)d_in[12];
  const float* r0_w   = (const float*)d_in[13];
  const float* r1_w   = (const float*)d_in[14];
  const float* r1_b   = (const float*)d_in[15];
  const float* r2_w   = (const float*)d_in[16];
  const float* r3_w   = (const float*)d_in[17];
  const float* r3_b   = (const float*)d_in[18];
  const float* l1_w   = (const float*)d_in[19];
  const float* l1_b   = (const float*)d_in[20];
  const float* l3_w   = (const float*)d_in[21];
  const float* l3_b   = (const float*)d_in[22];
  const float* ef     = (const float*)d_in[23];
  const float* linc   = (const float*)d_in[24];
  const float* rinc   = (const float*)d_in[25];
  const float* cap    = (const float*)d_in[26];
  const int*   pidx   = (const int*)d_in[27];
  float* out = (float*)d_out;

  float* ws   = (float*)d_ws;
  float* xbuf = ws + X_OFF;
  float* t4   = ws + T4_OFF;
  float* t3   = ws + T3_OFF;
  float* kb   = ws + KB_OFF;
  float* yg   = ws + YG_OFF;
  float* hbuf = ws + HB_OFF;
  float* res4 = ws + RES_OFF;
  float* part = ws + X_OFF;   // aliases x/t4/t3/kb (dead after k_eagg)
  int* ib = (int*)(ws + INT_OFF);
  int* lidx = ib;
  int* ridx = ib + 4096;
  int* part_start = ib + 8192;
  int2* pe2 = (int2*)(ib + 8704);   // 4096 int2 = 8192 ints

  hipLaunchKernelGGL(k_dc, dim3(3584), dim3(256), 0, stream,
                     linc, rinc, lidx, ridx, x1, conv_w, conv_b, xbuf);
  hipLaunchKernelGGL(k_prep, dim3(1857), dim3(256), 0, stream,
                     xbuf, pidx, k3_w, k4_w, x2, k2_w, ef, k1_w, k1_b,
                     r1_w, r1_b, r2_w, cap, lidx, ridx,
                     t4, t3, kb, hbuf, part_start, pe2);
  hipLaunchKernelGGL(k_eagg, dim3(256), dim3(512), 0, stream,
                     xbuf, kb, t3, t4, k5_w, k5_b, pe2, part_start,
                     gc_w, gc_b, yg);
  hipLaunchKernelGGL(k_r0, dim3(256), dim3(256), 0, stream, yg, r0_w, part);
  hipLaunchKernelGGL(k_r0red, dim3(256), dim3(256), 0, stream, part, hbuf);
  hipLaunchKernelGGL(k_wt_res, dim3(256), dim3(256), 0, stream, hbuf, r3_w, r3_b, yg, res4);
  hipLaunchKernelGGL(k_final, dim3(64), dim3(128), 0, stream,
                     res4, x2, l1_w, l1_b, l3_w, l3_b, out);
}